// Round 2
// baseline (2150.179 us; speedup 1.0000x reference)
//
#include <hip/hip_runtime.h>
#include <hip/hip_bf16.h>

typedef float f32x4 __attribute__((ext_vector_type(4)));
typedef __bf16 bf16x8 __attribute__((ext_vector_type(8)));

#define DEV __device__ __forceinline__

namespace {

constexpr int PIXP = 912;   // padded pixels (57 tiles of 16)
constexpr int NT   = 57;    // pixel tiles
constexpr int XS   = 40;    // x_lds row stride (elems): 80B, 16B-aligned, 2-way bank phase
constexpr int YS   = 24;    // Y_buf row stride: 48B
constexpr int CS   = 40;    // x1c/x2t row stride: 80B

constexpr int E_XS = PIXP * XS;        // 36480
constexpr int E_MS = PIXP;             // 912
constexpr int E_M0 = PIXP;             // 912
constexpr int E_Y  = PIXP * YS;        // 21888
constexpr int E_C  = 8 * 32 * CS;      // 10240
constexpr int BF16_ELEMS = E_XS + E_MS + E_M0 + E_Y + 2 * E_C;   // 80672
constexpr int SMEM_BYTES = BF16_ELEMS * 2 + 400 * 4;             // 162944 <= 163840

DEV f32x4 mfma16(bf16x8 a, bf16x8 b, f32x4 c) {
    return __builtin_amdgcn_mfma_f32_16x16x32_bf16(a, b, c, 0, 0, 0);
}

DEV bf16x8 load8(const __bf16* p) {   // 16B-aligned by construction -> ds_read_b128
    return *(const bf16x8*)p;
}

} // namespace

// One workgroup per batch element. 8 waves.
// LDS map: xs[912][40] (x, pixel-major, ch 40..: zero) | Ms[912] | M0[912] |
//          Yb[912][24] (16 k-slots + zero pad) | x1c[8][32][40] ([c][i][k]) |
//          x2t[8][32][40] ([c][j][k] = X2^T) | xo[5][2][40] f32 feature sums.
// All K padding is enforced on the WEIGHT side (predicated->0 in registers);
// LDS is zero-initialized once so out-of-range bf16 reads are always finite.
//
// __launch_bounds__(512, 1): LDS (163KB) forces 1 block/CU regardless, so the
// only effect of the 2nd arg is the VGPR cap. (512,2) capped at 128 VGPRs and
// spilled the 96-reg persistent accumulator to scratch -> 808 MB HBM writes
// (round-1 counters). With min-waves=1 the flat-work-group-size itself caps
// at 256 VGPRs (8-wave block must co-reside at 2 waves/SIMD), which fits the
// ~170-reg peak pressure with no spill.
__global__ __launch_bounds__(512, 1) void ppgn_fused(
    const float* __restrict__ X2g, const float* __restrict__ Mg,
    const float* __restrict__ w11, const float* __restrict__ w12,
    const float* __restrict__ w13, const float* __restrict__ wAg,
    const float* __restrict__ wBg, const float* __restrict__ wCg,
    const float* __restrict__ h1w, const float* __restrict__ h1b,
    float* __restrict__ out)
{
    extern __shared__ char smem[];
    __bf16* xs  = (__bf16*)smem;
    __bf16* MsL = xs + E_XS;
    __bf16* M0L = MsL + E_MS;
    __bf16* Yb  = M0L + E_M0;
    __bf16* x1c = Yb + E_Y;
    __bf16* x2t = x1c + E_C;
    float*  xo  = (float*)(x2t + E_C);

    const int tid  = threadIdx.x;
    const int wv   = tid >> 6;     // wave 0..7
    const int lane = tid & 63;
    const int lq   = lane & 15;    // fragment col/row selector
    const int lh   = lane >> 4;    // k-group 0..3
    const int b    = blockIdx.x;

    // ---- zero all LDS ----
    {
        unsigned int* p = (unsigned int*)smem;
        for (int i = tid; i < SMEM_BYTES / 4; i += 512) p[i] = 0u;
    }
    __syncthreads();

    // ---- stage inputs: x (3 ch) and masks ----
    {
        const float* xb = X2g + b * 2700;
        for (int idx = tid; idx < 2700; idx += 512) {
            int c  = idx / 900;
            int px = idx - c * 900;
            xs[px * XS + c] = (__bf16)xb[idx];
        }
        const float* mb = Mg + b * 1800;
        for (int px = tid; px < 900; px += 512) {
            float m0 = mb[px], m1 = mb[900 + px];
            MsL[px] = (__bf16)(m0 + m1);
            M0L[px] = (__bf16)m0;
        }
    }
    __syncthreads();

    for (int itb = 0; itb < 5; ++itb) {
        const float *wa, *wb, *wc;
        int kAB, sAB, kX, sC;
        if (itb == 0) { wa = w11; wb = w12; kAB = 3;  sAB = 3;  wc = w13; kX = 3;  sC = 43; }
        else {
            wa = wAg + (itb - 1) * 1600; wb = wBg + (itb - 1) * 1600; kAB = 40; sAB = 40;
            wc = wCg + (itb - 1) * 3200; kX = 40; sC = 80;
        }
        const bool two = (kAB > 32);

        // persistent xn accumulators: tile it (nt = wv + 8*it), Mtile m (o = 16m..)
        f32x4 acc[8][3];
        #pragma unroll
        for (int i = 0; i < 8; ++i) {
            #pragma unroll
            for (int m = 0; m < 3; ++m) acc[i][m] = f32x4{0.f, 0.f, 0.f, 0.f};
        }

        for (int cp = 0; cp < 3; ++cp) {           // chunk pairs {0,1},{2,3},{4}
            const int nch = (cp < 2) ? 2 : 1;
            for (int hc = 0; hc < nch; ++hc) {
                const int chunk = cp * 2 + hc;
                const int c0 = chunk * 8;
                // ---- Op1: x1/x2 conv for 8 channels (rows 0..7 = x1, 8..15 = x2) ----
                {
                    const float* rowp = ((lq < 8) ? wa : wb) + (c0 + (lq & 7)) * sAB;
                    bf16x8 af0, af1;
                    #pragma unroll
                    for (int e = 0; e < 8; ++e) {
                        const int k = 8 * lh + e;
                        af0[e] = (__bf16)((k < kAB) ? rowp[k] : 0.f);
                    }
                    if (two) {
                        #pragma unroll
                        for (int e = 0; e < 8; ++e) {
                            const int k = 32 + 8 * lh + e;
                            af1[e] = (__bf16)((k < kAB) ? rowp[k] : 0.f);
                        }
                    }
                    #pragma unroll
                    for (int it = 0; it < 8; ++it) {
                        const int nt = wv + 8 * it;
                        if (nt < NT) {
                            const int px = nt * 16 + lq;
                            const __bf16* bp = xs + px * XS + 8 * lh;
                            f32x4 a4 = f32x4{0.f, 0.f, 0.f, 0.f};
                            a4 = mfma16(af0, load8(bp), a4);
                            if (two) a4 = mfma16(af1, load8(bp + 32), a4);
                            if (px < 900) {
                                const float ms = (float)MsL[px];
                                const int i30 = px / 30;
                                const int j30 = px - i30 * 30;
                                #pragma unroll
                                for (int r = 0; r < 4; ++r) {
                                    const int o = 4 * lh + r;
                                    const __bf16 hv = (__bf16)fmaxf(a4[r] * ms, 0.f);
                                    if (o < 8) x1c[(o * 32 + i30) * CS + j30] = hv;       // [c][i][k=j]
                                    else       x2t[((o - 8) * 32 + j30) * CS + i30] = hv; // [c][j][k=i]
                                }
                            }
                        }
                    }
                }
                __syncthreads();
                // ---- Op2: per-channel 30x30 spatial matmul (one channel per wave) ----
                {
                    const __bf16* ab = x1c + wv * 32 * CS;
                    const __bf16* bb = x2t + wv * 32 * CS;
                    bf16x8 aA[2], bB[2];
                    #pragma unroll
                    for (int m = 0; m < 2; ++m) aA[m] = load8(ab + (m * 16 + lq) * CS + 8 * lh);
                    #pragma unroll
                    for (int n = 0; n < 2; ++n) bB[n] = load8(bb + (n * 16 + lq) * CS + 8 * lh);
                    const int slot = 8 * (chunk & 1) + wv;
                    #pragma unroll
                    for (int m = 0; m < 2; ++m) {
                        #pragma unroll
                        for (int n = 0; n < 2; ++n) {
                            f32x4 ay = f32x4{0.f, 0.f, 0.f, 0.f};
                            ay = mfma16(aA[m], bB[n], ay);
                            #pragma unroll
                            for (int r = 0; r < 4; ++r) {
                                const int i = m * 16 + 4 * lh + r;
                                const int j = n * 16 + lq;
                                if (i < 30 && j < 30) {
                                    const int px = i * 30 + j;
                                    Yb[px * YS + slot] = (__bf16)(ay[r] * (float)MsL[px]);
                                }
                            }
                        }
                    }
                }
                __syncthreads();
            }
            // ---- Op3 partial: xn += wc[:, cp*16 .. cp*16+16) @ Y(16 slots) ----
            {
                bf16x8 yf[3];
                #pragma unroll
                for (int m = 0; m < 3; ++m) {
                    const int o = m * 16 + lq;
                    #pragma unroll
                    for (int e = 0; e < 8; ++e) {
                        const int kl = 8 * lh + e;           // 0..31; slots >=16 are zero-weight
                        const int kg = cp * 16 + kl;
                        yf[m][e] = (__bf16)((o < 40 && kl < 16 && kg < 40) ? wc[o * sC + kg] : 0.f);
                    }
                }
                #pragma unroll
                for (int it = 0; it < 8; ++it) {
                    const int nt = wv + 8 * it;
                    if (nt < NT) {
                        const bf16x8 bf = load8(Yb + (nt * 16 + lq) * YS + 8 * lh);
                        #pragma unroll
                        for (int m = 0; m < 3; ++m) acc[it][m] = mfma16(yf[m], bf, acc[it][m]);
                    }
                }
            }
            __syncthreads();
        }
        // ---- Op3 x-part: xn += wc[:, 40:40+kX) @ x ----
        {
            bf16x8 xf0[3], xf1[3];
            #pragma unroll
            for (int m = 0; m < 3; ++m) {
                const int o = m * 16 + lq;
                #pragma unroll
                for (int e = 0; e < 8; ++e) {
                    const int k = 8 * lh + e;
                    xf0[m][e] = (__bf16)((o < 40 && k < kX) ? wc[o * sC + 40 + k] : 0.f);
                }
            }
            const bool twoX = (kX > 32);
            if (twoX) {
                #pragma unroll
                for (int m = 0; m < 3; ++m) {
                    const int o = m * 16 + lq;
                    #pragma unroll
                    for (int e = 0; e < 8; ++e) {
                        const int k = 32 + 8 * lh + e;
                        xf1[m][e] = (__bf16)((o < 40 && k < kX) ? wc[o * sC + 40 + k] : 0.f);
                    }
                }
            }
            #pragma unroll
            for (int it = 0; it < 8; ++it) {
                const int nt = wv + 8 * it;
                if (nt < NT) {
                    const __bf16* bp = xs + (nt * 16 + lq) * XS + 8 * lh;
                    const bf16x8 b0 = load8(bp);
                    #pragma unroll
                    for (int m = 0; m < 3; ++m) acc[it][m] = mfma16(xf0[m], b0, acc[it][m]);
                    if (twoX) {
                        const bf16x8 b1 = load8(bp + 32);
                        #pragma unroll
                        for (int m = 0; m < 3; ++m) acc[it][m] = mfma16(xf1[m], b1, acc[it][m]);
                    }
                }
            }
        }
        __syncthreads();   // all x reads complete before overwrite
        // ---- epilogue: xn = relu(acc*Ms); xo sums (fp32, pre-rounding); write new x ----
        {
            float xoA[3][4], xoB[3][4];
            #pragma unroll
            for (int m = 0; m < 3; ++m) {
                #pragma unroll
                for (int r = 0; r < 4; ++r) { xoA[m][r] = 0.f; xoB[m][r] = 0.f; }
            }
            #pragma unroll
            for (int it = 0; it < 8; ++it) {
                const int nt = wv + 8 * it;
                if (nt < NT) {
                    const int px = nt * 16 + lq;
                    if (px < 900) {
                        const float ms = (float)MsL[px];
                        const float m0 = (float)M0L[px];
                        const float m1 = ms - m0;
                        #pragma unroll
                        for (int m = 0; m < 3; ++m) {
                            #pragma unroll
                            for (int r = 0; r < 4; ++r) {
                                const int o = m * 16 + 4 * lh + r;
                                if (o < 40) {
                                    const float v = fmaxf(acc[it][m][r] * ms, 0.f);
                                    xoA[m][r] += v * m0;
                                    xoB[m][r] += v * m1;
                                    xs[px * XS + o] = (__bf16)v;
                                }
                            }
                        }
                    }
                }
            }
            #pragma unroll
            for (int m = 0; m < 3; ++m) {
                #pragma unroll
                for (int r = 0; r < 4; ++r) {
                    float a = xoA[m][r], b2 = xoB[m][r];
                    #pragma unroll
                    for (int d = 1; d < 16; d <<= 1) {
                        a  += __shfl_xor(a, d, 64);
                        b2 += __shfl_xor(b2, d, 64);
                    }
                    const int o = m * 16 + 4 * lh + r;
                    if (lq == 0 && o < 40) {
                        atomicAdd(&xo[itb * 80 + o], a);
                        atomicAdd(&xo[itb * 80 + 40 + o], b2);
                    }
                }
            }
        }
        __syncthreads();
    }

    // ---- head: out = relu(feat @ h1w^T + h1b), feat = xo[400] ----
    {
        const int hh = wv * 4 + lh;   // 0..31
        float s = 0.f;
        #pragma unroll
        for (int k2 = 0; k2 < 25; ++k2) {
            const int f = lq + 16 * k2;
            s += xo[f] * h1w[hh * 400 + f];
        }
        #pragma unroll
        for (int d = 1; d < 16; d <<= 1) s += __shfl_xor(s, d, 64);
        if (lq == 0) out[b * 32 + hh] = fmaxf(s + h1b[hh], 0.f);
    }
}

extern "C" void kernel_launch(void* const* d_in, const int* in_sizes, int n_in,
                              void* d_out, int out_size, void* d_ws, size_t ws_size,
                              hipStream_t stream) {
    (void)in_sizes; (void)n_in; (void)d_ws; (void)ws_size; (void)out_size;
    const float* X2  = (const float*)d_in[0];
    const float* M   = (const float*)d_in[1];
    const float* w11 = (const float*)d_in[2];
    const float* w12 = (const float*)d_in[3];
    const float* w13 = (const float*)d_in[4];
    const float* wA  = (const float*)d_in[5];
    const float* wB  = (const float*)d_in[6];
    const float* wC  = (const float*)d_in[7];
    const float* h1w = (const float*)d_in[8];
    const float* h1b = (const float*)d_in[9];
    float* out = (float*)d_out;

    (void)hipFuncSetAttribute(reinterpret_cast<const void*>(ppgn_fused),
                              hipFuncAttributeMaxDynamicSharedMemorySize, SMEM_BYTES);
    ppgn_fused<<<2048, 512, SMEM_BYTES, stream>>>(X2, M, w11, w12, w13,
                                                  wA, wB, wC, h1w, h1b, out);
}

// Round 3
// 1969.461 us; speedup vs baseline: 1.0918x; 1.0918x over previous
//
#include <hip/hip_runtime.h>
#include <hip/hip_bf16.h>

typedef float f32x4 __attribute__((ext_vector_type(4)));
typedef __bf16 bf16x8 __attribute__((ext_vector_type(8)));

#define DEV __device__ __forceinline__

namespace {

constexpr int PIXP = 912;   // padded pixels (57 tiles of 16)
constexpr int NT   = 57;    // pixel tiles
constexpr int XS   = 40;    // x_lds row stride (elems): 80B, 16B-aligned, 2-way bank phase
constexpr int YS   = 24;    // Y_buf row stride: 48B
constexpr int CS   = 40;    // x1c/x2t row stride: 80B

constexpr int E_XS = PIXP * XS;        // 36480
constexpr int E_MS = PIXP;             // 912
constexpr int E_M0 = PIXP;             // 912
constexpr int E_Y  = PIXP * YS;        // 21888
constexpr int E_C  = 8 * 32 * CS;      // 10240
constexpr int BF16_ELEMS = E_XS + E_MS + E_M0 + E_Y + 2 * E_C;   // 80672
constexpr int SMEM_BYTES = BF16_ELEMS * 2 + 400 * 4;             // 162944 <= 163840

DEV f32x4 mfma16(bf16x8 a, bf16x8 b, f32x4 c) {
    return __builtin_amdgcn_mfma_f32_16x16x32_bf16(a, b, c, 0, 0, 0);
}

DEV bf16x8 load8(const __bf16* p) {   // 16B-aligned by construction -> ds_read_b128
    return *(const bf16x8*)p;
}

} // namespace

// One workgroup per batch element. 8 waves. Register-pressure-shaped so peak
// live state stays under a 128-VGPR budget (rounds 1-2: allocator pinned at
// 128 regardless of __launch_bounds__, spilling ~770B/thread -> 808 MB HBM
// writes). acc[8][3] (96 regs, persistent xn accumulator) + <=24 transient.
__global__ __attribute__((amdgpu_flat_work_group_size(512, 512)))
           __attribute__((amdgpu_waves_per_eu(1, 2)))
void ppgn_fused_v3(
    const float* __restrict__ X2g, const float* __restrict__ Mg,
    const float* __restrict__ w11, const float* __restrict__ w12,
    const float* __restrict__ w13, const float* __restrict__ wAg,
    const float* __restrict__ wBg, const float* __restrict__ wCg,
    const float* __restrict__ h1w, const float* __restrict__ h1b,
    float* __restrict__ out)
{
    extern __shared__ char smem[];
    __bf16* xs  = (__bf16*)smem;
    __bf16* MsL = xs + E_XS;
    __bf16* M0L = MsL + E_MS;
    __bf16* Yb  = M0L + E_M0;
    __bf16* x1c = Yb + E_Y;
    __bf16* x2t = x1c + E_C;
    float*  xo  = (float*)(x2t + E_C);

    const int tid  = threadIdx.x;
    const int wv   = tid >> 6;     // wave 0..7
    const int lane = tid & 63;
    const int lq   = lane & 15;    // fragment col/row selector
    const int lh   = lane >> 4;    // k-group 0..3
    const int b    = blockIdx.x;

    // ---- zero all LDS ----
    {
        unsigned int* p = (unsigned int*)smem;
        for (int i = tid; i < SMEM_BYTES / 4; i += 512) p[i] = 0u;
    }
    __syncthreads();

    // ---- stage inputs: x (3 ch) and masks ----
    {
        const float* xb = X2g + b * 2700;
        for (int idx = tid; idx < 2700; idx += 512) {
            int c  = idx / 900;
            int px = idx - c * 900;
            xs[px * XS + c] = (__bf16)xb[idx];
        }
        const float* mb = Mg + b * 1800;
        for (int px = tid; px < 900; px += 512) {
            float m0 = mb[px], m1 = mb[900 + px];
            MsL[px] = (__bf16)(m0 + m1);
            M0L[px] = (__bf16)m0;
        }
    }
    __syncthreads();

    for (int itb = 0; itb < 5; ++itb) {
        const float *wa, *wb, *wc;
        int kAB, sAB, kX, sC;
        if (itb == 0) { wa = w11; wb = w12; kAB = 3;  sAB = 3;  wc = w13; kX = 3;  sC = 43; }
        else {
            wa = wAg + (itb - 1) * 1600; wb = wBg + (itb - 1) * 1600; kAB = 40; sAB = 40;
            wc = wCg + (itb - 1) * 3200; kX = 40; sC = 80;
        }
        const bool two = (kAB > 32);

        // persistent xn accumulators: tile it (nt = wv + 8*it), Mtile m (o = 16m..)
        f32x4 acc[8][3];
        #pragma unroll
        for (int i = 0; i < 8; ++i) {
            #pragma unroll
            for (int m = 0; m < 3; ++m) acc[i][m] = f32x4{0.f, 0.f, 0.f, 0.f};
        }

        for (int cp = 0; cp < 3; ++cp) {           // chunk pairs {0,1},{2,3},{4}
            const int nch = (cp < 2) ? 2 : 1;
            for (int hc = 0; hc < nch; ++hc) {
                const int chunk = cp * 2 + hc;
                const int c0 = chunk * 8;
                // ---- Op1: x1/x2 conv for 8 channels (rows 0..7 = x1, 8..15 = x2) ----
                {
                    const float* rowp = ((lq < 8) ? wa : wb) + (c0 + (lq & 7)) * sAB;
                    bf16x8 af0, af1;
                    #pragma unroll
                    for (int e = 0; e < 8; ++e) {
                        const int k = 8 * lh + e;
                        af0[e] = (__bf16)((k < kAB) ? rowp[k] : 0.f);
                    }
                    if (two) {
                        #pragma unroll
                        for (int e = 0; e < 8; ++e) {
                            const int k = 32 + 8 * lh + e;
                            af1[e] = (__bf16)((k < kAB) ? rowp[k] : 0.f);
                        }
                    }
                    #pragma unroll
                    for (int it = 0; it < 8; ++it) {
                        const int nt = wv + 8 * it;
                        if (nt < NT) {
                            const int px = nt * 16 + lq;
                            const __bf16* bp = xs + px * XS + 8 * lh;
                            f32x4 a4 = f32x4{0.f, 0.f, 0.f, 0.f};
                            a4 = mfma16(af0, load8(bp), a4);
                            if (two) a4 = mfma16(af1, load8(bp + 32), a4);
                            if (px < 900) {
                                const float ms = (float)MsL[px];
                                const int i30 = px / 30;
                                const int j30 = px - i30 * 30;
                                #pragma unroll
                                for (int r = 0; r < 4; ++r) {
                                    const int o = 4 * lh + r;
                                    const __bf16 hv = (__bf16)fmaxf(a4[r] * ms, 0.f);
                                    if (o < 8) x1c[(o * 32 + i30) * CS + j30] = hv;       // [c][i][k=j]
                                    else       x2t[((o - 8) * 32 + j30) * CS + i30] = hv; // [c][j][k=i]
                                }
                            }
                        }
                    }
                }
                __syncthreads();
                // ---- Op2: per-channel 30x30 spatial matmul (one channel per wave).
                // Fragments loaded inside the m/n loops (not up front): 8 live
                // transient regs instead of 16+.
                {
                    const __bf16* ab = x1c + wv * 32 * CS;
                    const __bf16* bb = x2t + wv * 32 * CS;
                    const int slot = 8 * (chunk & 1) + wv;
                    #pragma unroll
                    for (int m = 0; m < 2; ++m) {
                        const bf16x8 aAm = load8(ab + (m * 16 + lq) * CS + 8 * lh);
                        #pragma unroll
                        for (int n = 0; n < 2; ++n) {
                            const bf16x8 bBn = load8(bb + (n * 16 + lq) * CS + 8 * lh);
                            f32x4 ay = f32x4{0.f, 0.f, 0.f, 0.f};
                            ay = mfma16(aAm, bBn, ay);
                            #pragma unroll
                            for (int r = 0; r < 4; ++r) {
                                const int i = m * 16 + 4 * lh + r;
                                const int j = n * 16 + lq;
                                if (i < 30 && j < 30) {
                                    const int px = i * 30 + j;
                                    Yb[px * YS + slot] = (__bf16)(ay[r] * (float)MsL[px]);
                                }
                            }
                        }
                        __builtin_amdgcn_sched_barrier(0);
                    }
                }
                __syncthreads();
            }
            // ---- Op3 partial: xn += wc[:, cp*16 .. cp*16+16) @ Y(16 slots) ----
            {
                bf16x8 yf[3];
                #pragma unroll
                for (int m = 0; m < 3; ++m) {
                    const int o = m * 16 + lq;
                    #pragma unroll
                    for (int e = 0; e < 8; ++e) {
                        const int kl = 8 * lh + e;           // 0..31; slots >=16 are zero-weight
                        const int kg = cp * 16 + kl;
                        yf[m][e] = (__bf16)((o < 40 && kl < 16 && kg < 40) ? wc[o * sC + kg] : 0.f);
                    }
                }
                #pragma unroll
                for (int it = 0; it < 8; ++it) {
                    const int nt = wv + 8 * it;
                    if (nt < NT) {
                        const bf16x8 bf = load8(Yb + (nt * 16 + lq) * YS + 8 * lh);
                        #pragma unroll
                        for (int m = 0; m < 3; ++m) acc[it][m] = mfma16(yf[m], bf, acc[it][m]);
                    }
                }
            }
            __syncthreads();
        }
        // ---- Op3 x-part: xn += wc[:, 40:40+kX) @ x. Two sequential k-passes
        // so only one 12-reg weight-fragment set is live at a time.
        {
            {   // pass 0: k = 0..31
                bf16x8 xf[3];
                #pragma unroll
                for (int m = 0; m < 3; ++m) {
                    const int o = m * 16 + lq;
                    #pragma unroll
                    for (int e = 0; e < 8; ++e) {
                        const int k = 8 * lh + e;
                        xf[m][e] = (__bf16)((o < 40 && k < kX) ? wc[o * sC + 40 + k] : 0.f);
                    }
                }
                #pragma unroll
                for (int it = 0; it < 8; ++it) {
                    const int nt = wv + 8 * it;
                    if (nt < NT) {
                        const bf16x8 b0 = load8(xs + (nt * 16 + lq) * XS + 8 * lh);
                        #pragma unroll
                        for (int m = 0; m < 3; ++m) acc[it][m] = mfma16(xf[m], b0, acc[it][m]);
                    }
                }
            }
            __builtin_amdgcn_sched_barrier(0);
            if (kX > 32) {   // pass 1: k = 32..39
                bf16x8 xf[3];
                #pragma unroll
                for (int m = 0; m < 3; ++m) {
                    const int o = m * 16 + lq;
                    #pragma unroll
                    for (int e = 0; e < 8; ++e) {
                        const int k = 32 + 8 * lh + e;
                        xf[m][e] = (__bf16)((o < 40 && k < kX) ? wc[o * sC + 40 + k] : 0.f);
                    }
                }
                #pragma unroll
                for (int it = 0; it < 8; ++it) {
                    const int nt = wv + 8 * it;
                    if (nt < NT) {
                        const bf16x8 b1 = load8(xs + (nt * 16 + lq) * XS + 8 * lh + 32);
                        #pragma unroll
                        for (int m = 0; m < 3; ++m) acc[it][m] = mfma16(xf[m], b1, acc[it][m]);
                    }
                }
            }
        }
        __syncthreads();   // all x reads complete before overwrite
        // ---- epilogue: xn = relu(acc*Ms); xo sums (fp32, pre-rounding); write
        // new x. Per-m sequencing: 8 live accum regs instead of 24.
        {
            #pragma unroll
            for (int m = 0; m < 3; ++m) {
                float sA[4] = {0.f, 0.f, 0.f, 0.f};
                float sB[4] = {0.f, 0.f, 0.f, 0.f};
                #pragma unroll
                for (int it = 0; it < 8; ++it) {
                    const int nt = wv + 8 * it;
                    if (nt < NT) {
                        const int px = nt * 16 + lq;
                        if (px < 900) {
                            const float ms = (float)MsL[px];
                            const float m0 = (float)M0L[px];
                            const float m1 = ms - m0;
                            #pragma unroll
                            for (int r = 0; r < 4; ++r) {
                                const int o = m * 16 + 4 * lh + r;
                                if (o < 40) {
                                    const float v = fmaxf(acc[it][m][r] * ms, 0.f);
                                    sA[r] += v * m0;
                                    sB[r] += v * m1;
                                    xs[px * XS + o] = (__bf16)v;
                                }
                            }
                        }
                    }
                }
                #pragma unroll
                for (int r = 0; r < 4; ++r) {
                    float a = sA[r], b2 = sB[r];
                    #pragma unroll
                    for (int d = 1; d < 16; d <<= 1) {
                        a  += __shfl_xor(a, d, 64);
                        b2 += __shfl_xor(b2, d, 64);
                    }
                    const int o = m * 16 + 4 * lh + r;
                    if (lq == 0 && o < 40) {
                        atomicAdd(&xo[itb * 80 + o], a);
                        atomicAdd(&xo[itb * 80 + 40 + o], b2);
                    }
                }
                __builtin_amdgcn_sched_barrier(0);
            }
        }
        __syncthreads();
    }

    // ---- head: out = relu(feat @ h1w^T + h1b), feat = xo[400] ----
    {
        const int hh = wv * 4 + lh;   // 0..31
        float s = 0.f;
        #pragma unroll
        for (int k2 = 0; k2 < 25; ++k2) {
            const int f = lq + 16 * k2;
            s += xo[f] * h1w[hh * 400 + f];
        }
        #pragma unroll
        for (int d = 1; d < 16; d <<= 1) s += __shfl_xor(s, d, 64);
        if (lq == 0) out[b * 32 + hh] = fmaxf(s + h1b[hh], 0.f);
    }
}

extern "C" void kernel_launch(void* const* d_in, const int* in_sizes, int n_in,
                              void* d_out, int out_size, void* d_ws, size_t ws_size,
                              hipStream_t stream) {
    (void)in_sizes; (void)n_in; (void)d_ws; (void)ws_size; (void)out_size;
    const float* X2  = (const float*)d_in[0];
    const float* M   = (const float*)d_in[1];
    const float* w11 = (const float*)d_in[2];
    const float* w12 = (const float*)d_in[3];
    const float* w13 = (const float*)d_in[4];
    const float* wA  = (const float*)d_in[5];
    const float* wB  = (const float*)d_in[6];
    const float* wC  = (const float*)d_in[7];
    const float* h1w = (const float*)d_in[8];
    const float* h1b = (const float*)d_in[9];
    float* out = (float*)d_out;

    (void)hipFuncSetAttribute(reinterpret_cast<const void*>(ppgn_fused_v3),
                              hipFuncAttributeMaxDynamicSharedMemorySize, SMEM_BYTES);
    ppgn_fused_v3<<<2048, 512, SMEM_BYTES, stream>>>(X2, M, w11, w12, w13,
                                                     wA, wB, wC, h1w, h1b, out);
}

// Round 6
// 1567.854 us; speedup vs baseline: 1.3714x; 1.2562x over previous
//
#include <hip/hip_runtime.h>
#include <hip/hip_bf16.h>

typedef float f32x4 __attribute__((ext_vector_type(4)));
typedef __bf16 bf16x8 __attribute__((ext_vector_type(8)));

#define DEV __device__ __forceinline__

namespace {

// Image padded 30x30 -> 32x32 internally. Masks are zero-padded, so every
// lane is valid everywhere: no divisions (>>5, &31), no edge branches, and
// pad pixels self-clean (v = relu(acc*0) = 0).
constexpr int XS   = 40;                 // xs row stride (elems/pixel)
constexpr int CSTR = 32 * 40 + 8;        // 1288: x1c/x2t channel stride.
// CSTR % 8 == 0 keeps ds_read_b128 16B-aligned; CSTR % 16 == 8 puts the two
// lh-groups of a scatter-write instruction on disjoint bank halves (+16dw).
constexpr int E_XS = 1024 * XS + 64;     // 41024 (+slack for k=32..63 overreads)
constexpr int E_M  = 1024;
constexpr int E_Y  = 1024 * 16 + 32;     // 16416 (16 slots/pixel + slack)
constexpr int E_C  = 8 * CSTR;           // 10304
constexpr int BF16_ELEMS = E_XS + 2 * E_M + E_Y + 2 * E_C;   // 80096
constexpr int SMEM_BYTES = BF16_ELEMS * 2 + 400 * 4;         // 161792 <= 163840

DEV f32x4 mfma16(bf16x8 a, bf16x8 b, f32x4 c) {
    return __builtin_amdgcn_mfma_f32_16x16x32_bf16(a, b, c, 0, 0, 0);
}
DEV bf16x8 load8(const __bf16* p) { return *(const bf16x8*)p; }   // ds_read_b128

} // namespace

// One workgroup per batch element, 8 waves, tiles nt = 8*wv + it (8 each).
// amdgpu_waves_per_eu(2,2): LDS (158KB) pins 1 block/CU = exactly 2 waves/EU;
// declaring it should lift the VGPR cap to 256 (dynamic-LDS makes the
// compiler's occupancy heuristic assume more waves fit -> 128 cap -> spill).
__global__ __attribute__((amdgpu_flat_work_group_size(512, 512)))
           __attribute__((amdgpu_waves_per_eu(2, 2)))
void ppgn_fused_v4(
    const float* __restrict__ X2g, const float* __restrict__ Mg,
    const float* __restrict__ w11, const float* __restrict__ w12,
    const float* __restrict__ w13, const float* __restrict__ wAg,
    const float* __restrict__ wBg, const float* __restrict__ wCg,
    const float* __restrict__ h1w, const float* __restrict__ h1b,
    float* __restrict__ out)
{
    extern __shared__ char smem[];
    __bf16* xs  = (__bf16*)smem;          // [1024][40] pixel-major x
    __bf16* MsL = xs + E_XS;              // [1024] M0+M1 (0 in pad)
    __bf16* M0L = MsL + E_M;              // [1024] M0
    __bf16* Yb  = M0L + E_M;              // [1024][16] Y k-slots (XOR-swizzled)
    __bf16* x1c = Yb + E_Y;               // [8][32][40+] x1 chunk, [c][i][k=j]
    __bf16* x2t = x1c + E_C;              // [8][32][40+] x2^T chunk, [c][j][k=i]
    float*  xo  = (float*)(x2t + E_C);    // [5][2][40] feature sums

    const int tid  = threadIdx.x;
    const int wv   = tid >> 6;
    const int lane = tid & 63;
    const int lq   = lane & 15;
    const int lh   = lane >> 4;
    const int b    = blockIdx.x;

    // ---- zero all LDS (slack regions must be finite; xo needs 0) ----
    {
        unsigned int* p = (unsigned int*)smem;
        for (int i = tid; i < SMEM_BYTES / 4; i += 512) p[i] = 0u;
    }
    __syncthreads();

    // ---- stage x (3ch) and masks, zero-padded to 32x32 ----
    {
        const float* xb = X2g + b * 2700;
        for (int idx = tid; idx < 3072; idx += 512) {
            const int c = idx >> 10, px = idx & 1023;
            const int i = px >> 5, j = px & 31;
            const bool v = (i < 30) & (j < 30);
            xs[px * XS + c] = v ? (__bf16)xb[c * 900 + i * 30 + j] : (__bf16)0.f;
        }
        const float* mb = Mg + b * 1800;
        for (int px = tid; px < 1024; px += 512) {
            const int i = px >> 5, j = px & 31;
            const bool v = (i < 30) & (j < 30);
            const float m0 = v ? mb[i * 30 + j] : 0.f;
            const float m1 = v ? mb[900 + i * 30 + j] : 0.f;
            MsL[px] = (__bf16)(m0 + m1);
            M0L[px] = (__bf16)m0;
        }
    }
    __syncthreads();

    // ---- per-tile masks, persistent in registers (invariant all kernel) ----
    float msf[8], m0f[8];
    #pragma unroll
    for (int it = 0; it < 8; ++it) {
        const int px = (8 * wv + it) * 16 + lq;
        msf[it] = (float)MsL[px];
        m0f[it] = (float)M0L[px];
    }

    f32x4 acc[8][3];

    for (int itb = 0; itb < 5; ++itb) {
        const float *wa, *wb, *wc;
        int kAB, sAB, kX, sC;
        if (itb == 0) { wa = w11; wb = w12; kAB = 3;  sAB = 3;  wc = w13; kX = 3;  sC = 43; }
        else {
            wa = wAg + (itb - 1) * 1600; wb = wBg + (itb - 1) * 1600; kAB = 40; sAB = 40;
            wc = wCg + (itb - 1) * 3200; kX = 40; sC = 80;
        }
        const bool generic = (itb == 0);

        #pragma unroll
        for (int i = 0; i < 8; ++i)
            #pragma unroll
            for (int m = 0; m < 3; ++m) acc[i][m] = f32x4{0.f, 0.f, 0.f, 0.f};

        // Op1: conv -> x1 (rows 0..7) / x2 (rows 8..15) for one 8-ch chunk,
        // scattered into x1c [c][i][j] / x2t [c][j][i]. i = nt>>1 is uniform.
        auto OP1 = [&](int chunk) {
            const float* rowp = ((lq < 8) ? wa : wb) + (chunk * 8 + (lq & 7)) * sAB;
            bf16x8 af0, af1;
            if (!generic) {
                #pragma unroll
                for (int e = 0; e < 8; ++e) af0[e] = (__bf16)rowp[8 * lh + e];
                #pragma unroll
                for (int e = 0; e < 8; ++e) {        // k=32..39 only lh==0
                    const float v = rowp[(lh == 0) ? (32 + e) : e];
                    af1[e] = (lh == 0) ? (__bf16)v : (__bf16)0.f;
                }
            } else {
                #pragma unroll
                for (int e = 0; e < 8; ++e) {
                    const int k = 8 * lh + e;
                    const float v = rowp[(k < kAB) ? k : 0];
                    af0[e] = (k < kAB) ? (__bf16)v : (__bf16)0.f;
                }
            }
            #pragma unroll
            for (int it = 0; it < 8; ++it) {
                const int nt = 8 * wv + it;
                const __bf16* bp = xs + (nt * 16 + lq) * XS + 8 * lh;
                f32x4 a4 = f32x4{0.f, 0.f, 0.f, 0.f};
                a4 = mfma16(af0, load8(bp), a4);
                if (!generic) a4 = mfma16(af1, load8(bp + 32), a4);
                const float ms = msf[it];
                const int ib = (nt >> 1) * 40;            // i*40 (uniform)
                const int jj = ((nt & 1) << 4) + lq;      // j
                #pragma unroll
                for (int r = 0; r < 4; ++r) {
                    const int o = 4 * lh + r;
                    const __bf16 hv = (__bf16)fmaxf(a4[r] * ms, 0.f);
                    if (lh < 2) x1c[o * CSTR + ib + jj] = hv;
                    else        x2t[(o - 8) * CSTR + jj * 40 + (nt >> 1)] = hv;
                }
            }
        };

        // Op2: per-channel (c = chunk*8+wv) 32x32x32 spatial matmul -> Yb slot.
        auto OP2 = [&](int chunk) {
            const __bf16* ab = x1c + wv * CSTR;
            const __bf16* bb = x2t + wv * CSTR;
            const int slot = 8 * (chunk & 1) + wv;
            #pragma unroll
            for (int m = 0; m < 2; ++m) {
                const bf16x8 aAm = load8(ab + (m * 16 + lq) * 40 + 8 * lh);
                #pragma unroll
                for (int n = 0; n < 2; ++n) {
                    const bf16x8 bBn = load8(bb + (n * 16 + lq) * 40 + 8 * lh);
                    f32x4 ay = f32x4{0.f, 0.f, 0.f, 0.f};
                    ay = mfma16(aAm, bBn, ay);
                    #pragma unroll
                    for (int r = 0; r < 4; ++r) {
                        const int px = (m * 16 + 4 * lh + r) * 32 + n * 16 + lq;
                        const int swz = ((px >> 2) & 1) << 3;     // bank spread
                        Yb[px * 16 + (slot ^ swz)] = (__bf16)(ay[r] * (float)MsL[px]);
                    }
                }
            }
        };

        // Op3 partial: acc += wc[:, cp*16..+16) @ Y(16 slots)
        auto OP3 = [&](int cp) {
            bf16x8 yf[3];
            #pragma unroll
            for (int m = 0; m < 3; ++m) {
                const int o = m * 16 + lq;
                #pragma unroll
                for (int e = 0; e < 8; ++e) {
                    const int kl = 8 * lh + e, kg = cp * 16 + kl;
                    const bool ok = (o < 40) & (kl < 16) & (kg < 40);
                    const float v = wc[ok ? o * sC + kg : 0];
                    yf[m][e] = ok ? (__bf16)v : (__bf16)0.f;
                }
            }
            #pragma unroll
            for (int it = 0; it < 8; ++it) {
                const int px = (8 * wv + it) * 16 + lq;
                const int swz = ((px >> 2) & 1) << 3;
                const bf16x8 bf = load8(Yb + px * 16 + (8 * lh ^ swz));
                #pragma unroll
                for (int m = 0; m < 3; ++m) acc[it][m] = mfma16(yf[m], bf, acc[it][m]);
            }
        };

        // Op3 x-part: acc += wc[:, 40+koff..] @ x
        auto XP = [&](int koff) {
            bf16x8 xf[3];
            #pragma unroll
            for (int m = 0; m < 3; ++m) {
                const int o = m * 16 + lq;
                #pragma unroll
                for (int e = 0; e < 8; ++e) {
                    const int k = koff + 8 * lh + e;
                    const bool ok = (o < 40) & (k < kX);
                    const float v = wc[ok ? o * sC + 40 + k : 0];
                    xf[m][e] = ok ? (__bf16)v : (__bf16)0.f;
                }
            }
            #pragma unroll
            for (int it = 0; it < 8; ++it) {
                const bf16x8 b0 = load8(xs + ((8 * wv + it) * 16 + lq) * XS + koff + 8 * lh);
                #pragma unroll
                for (int m = 0; m < 3; ++m) acc[it][m] = mfma16(xf[m], b0, acc[it][m]);
            }
        };

        // 5 chunks; Op3(cp) merged with the next Op1 (independent LDS regions)
        OP1(0);           __syncthreads();
        OP2(0);           __syncthreads();
        OP1(1);           __syncthreads();
        OP2(1);           __syncthreads();
        OP3(0); OP1(2);   __syncthreads();
        OP2(2);           __syncthreads();
        OP1(3);           __syncthreads();
        OP2(3);           __syncthreads();
        OP3(1); OP1(4);   __syncthreads();
        OP2(4);           __syncthreads();
        OP3(2);                            // slots 8..15 stale but zero-weighted
        XP(0);
        if (kX > 32) XP(32);
        __syncthreads();                   // x reads done before overwrite

        // epilogue: xn = relu(acc*Ms); feature sums from fp32 pre-rounding
        #pragma unroll
        for (int m = 0; m < 3; ++m) {
            float sA[4] = {0.f, 0.f, 0.f, 0.f};
            float sB[4] = {0.f, 0.f, 0.f, 0.f};
            #pragma unroll
            for (int it = 0; it < 8; ++it) {
                const int px = (8 * wv + it) * 16 + lq;
                const float ms = msf[it];
                const float m0v = m0f[it];
                const float m1v = ms - m0v;
                #pragma unroll
                for (int r = 0; r < 4; ++r) {
                    const int o = m * 16 + 4 * lh + r;
                    if (o < 40) {
                        const float v = fmaxf(acc[it][m][r] * ms, 0.f);
                        xs[px * XS + o] = (__bf16)v;
                        sA[r] += v * m0v;
                        sB[r] += v * m1v;
                    }
                }
            }
            #pragma unroll
            for (int r = 0; r < 4; ++r) {
                float a = sA[r], b2 = sB[r];
                #pragma unroll
                for (int d = 1; d < 16; d <<= 1) {
                    a  += __shfl_xor(a, d, 64);
                    b2 += __shfl_xor(b2, d, 64);
                }
                const int o = m * 16 + 4 * lh + r;
                if (lq == 0 && o < 40) {
                    atomicAdd(&xo[itb * 80 + o], a);
                    atomicAdd(&xo[itb * 80 + 40 + o], b2);
                }
            }
        }
        __syncthreads();
    }

    // ---- head: out = relu(feat @ h1w^T + h1b) ----
    {
        const int hh = wv * 4 + lh;   // 0..31
        float s = 0.f;
        #pragma unroll
        for (int k2 = 0; k2 < 25; ++k2) {
            const int f = lq + 16 * k2;
            s += xo[f] * h1w[hh * 400 + f];
        }
        #pragma unroll
        for (int d = 1; d < 16; d <<= 1) s += __shfl_xor(s, d, 64);
        if (lq == 0) out[b * 32 + hh] = fmaxf(s + h1b[hh], 0.f);
    }
}

extern "C" void kernel_launch(void* const* d_in, const int* in_sizes, int n_in,
                              void* d_out, int out_size, void* d_ws, size_t ws_size,
                              hipStream_t stream) {
    (void)in_sizes; (void)n_in; (void)d_ws; (void)ws_size; (void)out_size;
    const float* X2  = (const float*)d_in[0];
    const float* M   = (const float*)d_in[1];
    const float* w11 = (const float*)d_in[2];
    const float* w12 = (const float*)d_in[3];
    const float* w13 = (const float*)d_in[4];
    const float* wA  = (const float*)d_in[5];
    const float* wB  = (const float*)d_in[6];
    const float* wC  = (const float*)d_in[7];
    const float* h1w = (const float*)d_in[8];
    const float* h1b = (const float*)d_in[9];
    float* out = (float*)d_out;

    (void)hipFuncSetAttribute(reinterpret_cast<const void*>(ppgn_fused_v4),
                              hipFuncAttributeMaxDynamicSharedMemorySize, SMEM_BYTES);
    ppgn_fused_v4<<<2048, 512, SMEM_BYTES, stream>>>(X2, M, w11, w12, w13,
                                                     wA, wB, wC, h1w, h1b, out);
}